// Round 1
// baseline (168.195 us; speedup 1.0000x reference)
//
#include <hip/hip_runtime.h>
#include <math.h>

// SinkhornM: per-row fused MLP(8->32->16->9) + tau + sigmoid-shares +
// 10-iter 3x3 Sinkhorn + 4x4 assembly. B = 1,048,576 rows, f32.
//
// Strategy round 1:
//  - R=2 rows per thread (halves per-row uniform weight-load instr cost).
//  - Weights read straight from global with wave-uniform compile-time
//    offsets on fully unrolled loops -> backend should select s_load (SMEM),
//    keeping the LDS and vector-memory pipes free.
//  - v_rcp_f32 for Sinkhorn divides, __expf for exponentials (errors ~1e-6,
//    threshold is 2.9e-2).

#define EPS_F 1e-12f
#define QLOW  0.02f
#define QSPAN 0.96f   // HIGH - LOW

constexpr int R = 2;

__device__ __forceinline__ float frcp(float x) { return __builtin_amdgcn_rcpf(x); }
__device__ __forceinline__ float fsig(float x) { return frcp(1.0f + __expf(-x)); }

__global__ __launch_bounds__(256) void sinkhorn_fused(
    const float* __restrict__ margins,
    const float* __restrict__ W1, const float* __restrict__ b1,
    const float* __restrict__ W2, const float* __restrict__ b2,
    const float* __restrict__ W3, const float* __restrict__ b3,
    float* __restrict__ out, int n)
{
    const int tid  = blockIdx.x * blockDim.x + threadIdx.x;
    const int lane = tid & 63;
    // wave-interleaved row assignment: wave w owns rows [w*128, w*128+128),
    // thread handles rows base and base+64 -> every load/store instruction
    // is lane-contiguous within its stride class (full cache-line use).
    const int base = (tid >> 6) * (64 * R) + lane;

    const float4* __restrict__ m4  = (const float4*)margins;
    const float4* __restrict__ W1v = (const float4*)W1;  // (8,32) row-major
    const float4* __restrict__ W2v = (const float4*)W2;  // (32,16) row-major

    // ---- load margins (2 x float4 per row)
    float m[R][8];
#pragma unroll
    for (int r = 0; r < R; ++r) {
        const int row = base + 64 * r;
        const float4 a0 = m4[row * 2 + 0];
        const float4 a1 = m4[row * 2 + 1];
        m[r][0] = a0.x; m[r][1] = a0.y; m[r][2] = a0.z; m[r][3] = a0.w;
        m[r][4] = a1.x; m[r][5] = a1.y; m[r][6] = a1.z; m[r][7] = a1.w;
    }

    // ---- layer 1: h1 = relu(m @ W1 + b1)
    float h1[R][32];
#pragma unroll
    for (int j = 0; j < 32; ++j) {
        const float bb = b1[j];
#pragma unroll
        for (int r = 0; r < R; ++r) h1[r][j] = bb;
    }
#pragma unroll
    for (int k = 0; k < 8; ++k) {
#pragma unroll
        for (int j4 = 0; j4 < 8; ++j4) {
            const float4 w = W1v[k * 8 + j4];  // uniform address -> s_load
#pragma unroll
            for (int r = 0; r < R; ++r) {
                h1[r][j4*4+0] = fmaf(m[r][k], w.x, h1[r][j4*4+0]);
                h1[r][j4*4+1] = fmaf(m[r][k], w.y, h1[r][j4*4+1]);
                h1[r][j4*4+2] = fmaf(m[r][k], w.z, h1[r][j4*4+2]);
                h1[r][j4*4+3] = fmaf(m[r][k], w.w, h1[r][j4*4+3]);
            }
        }
    }
#pragma unroll
    for (int j = 0; j < 32; ++j)
#pragma unroll
        for (int r = 0; r < R; ++r) h1[r][j] = fmaxf(h1[r][j], 0.0f);

    // ---- layer 2: h2 = relu(h1 @ W2 + b2)
    float h2[R][16];
#pragma unroll
    for (int j = 0; j < 16; ++j) {
        const float bb = b2[j];
#pragma unroll
        for (int r = 0; r < R; ++r) h2[r][j] = bb;
    }
#pragma unroll
    for (int k = 0; k < 32; ++k) {
#pragma unroll
        for (int j4 = 0; j4 < 4; ++j4) {
            const float4 w = W2v[k * 4 + j4];
#pragma unroll
            for (int r = 0; r < R; ++r) {
                h2[r][j4*4+0] = fmaf(h1[r][k], w.x, h2[r][j4*4+0]);
                h2[r][j4*4+1] = fmaf(h1[r][k], w.y, h2[r][j4*4+1]);
                h2[r][j4*4+2] = fmaf(h1[r][k], w.z, h2[r][j4*4+2]);
                h2[r][j4*4+3] = fmaf(h1[r][k], w.w, h2[r][j4*4+3]);
            }
        }
    }
#pragma unroll
    for (int j = 0; j < 16; ++j)
#pragma unroll
        for (int r = 0; r < R; ++r) h2[r][j] = fmaxf(h2[r][j], 0.0f);

    // ---- layer 3: pars = h2 @ W3 + b3   (W3 is (16,9) row-major)
    float p[R][9];
#pragma unroll
    for (int j = 0; j < 9; ++j) {
        const float bb = b3[j];
#pragma unroll
        for (int r = 0; r < R; ++r) p[r][j] = bb;
    }
#pragma unroll
    for (int k = 0; k < 16; ++k) {
#pragma unroll
        for (int j = 0; j < 9; ++j) {
            const float w = W3[k * 9 + j];  // uniform scalar -> s_load
#pragma unroll
            for (int r = 0; r < R; ++r) p[r][j] = fmaf(h2[r][k], w, p[r][j]);
        }
    }

    // ---- per-row epilogue: tau, shares, sinkhorn, assembly
    float4* __restrict__ o4 = (float4*)out;
    float* __restrict__ oV = out + (size_t)n * 16;

#pragma unroll
    for (int r = 0; r < R; ++r) {
        const int row = base + 64 * r;

        // tau(exp(pars[0:4])) -> 3x3 A
        const float e0 = __expf(p[r][0]);
        const float e1 = __expf(p[r][1]);
        const float e2 = __expf(p[r][2]);
        const float e3 = __expf(p[r][3]);
        const float col0 = sqrtf(e0 * e1);
        const float col1 = sqrtf(e2 * e3);
        const float rw0  = sqrtf(e0 * e2);
        const float rw1  = sqrtf(e1 * e3);
        const float corn = sqrtf(rw0 * rw1);

        float A0 = e0,  A1 = e1,  A2 = col0;
        float A3 = e2,  A4 = e3,  A5 = col1;
        float A6 = rw0, A7 = rw1, A8 = corn;

        // shares
        const float s4 = QLOW + QSPAN * fsig(p[r][4]);
        const float s5 = QLOW + QSPAN * fsig(p[r][5]);
        const float s6 = QLOW + QSPAN * fsig(p[r][6]);
        const float s7 = QLOW + QSPAN * fsig(p[r][7]);

        const float M0 = m[r][0], M1 = m[r][1], M2 = m[r][2];
        const float F0 = m[r][3], F1 = m[r][4], F2 = m[r][5];

        // row margins (mucm0) and col margins (muc0f)
        const float rm0 = M0 * s4, rm1 = M1 * s5, rm2 = M2;
        const float cm0 = F0 * s6, cm1 = F1 * s7, cm2 = F2;
        // leftovers
        const float um0 = M0 * (1.0f - s4);
        const float um1 = M1 * (1.0f - s5);
        const float um2 = 0.0f;               // M2 * (1-1)
        const float uf0 = F0 * (1.0f - s6);
        const float uf1 = F1 * (1.0f - s7);
        const float uf2 = 0.0f;

        // ---- 10 Sinkhorn iterations: row-normalize then col-normalize
        for (int it = 0; it < 10; ++it) {
            float f0 = rm0 * frcp(A0 + A1 + A2 + EPS_F);
            float f1 = rm1 * frcp(A3 + A4 + A5 + EPS_F);
            float f2 = rm2 * frcp(A6 + A7 + A8 + EPS_F);
            A0 *= f0; A1 *= f0; A2 *= f0;
            A3 *= f1; A4 *= f1; A5 *= f1;
            A6 *= f2; A7 *= f2; A8 *= f2;
            float g0 = cm0 * frcp(A0 + A3 + A6 + EPS_F);
            float g1 = cm1 * frcp(A1 + A4 + A7 + EPS_F);
            float g2 = cm2 * frcp(A2 + A5 + A8 + EPS_F);
            A0 *= g0; A3 *= g0; A6 *= g0;
            A1 *= g1; A4 *= g1; A7 *= g1;
            A2 *= g2; A5 *= g2; A8 *= g2;
        }

        // ---- assemble 4x4 mus + V
        o4[row * 4 + 0] = make_float4(A0, A1, A2, um0);
        o4[row * 4 + 1] = make_float4(A3, A4, A5, um1);
        o4[row * 4 + 2] = make_float4(A6, A7, A8, um2);
        o4[row * 4 + 3] = make_float4(uf0, uf1, uf2, 0.0f);
        oV[row] = __expf(p[r][8]);
    }
}

extern "C" void kernel_launch(void* const* d_in, const int* in_sizes, int n_in,
                              void* d_out, int out_size, void* d_ws, size_t ws_size,
                              hipStream_t stream) {
    const float* margins = (const float*)d_in[0];
    const float* W1 = (const float*)d_in[1];
    const float* b1 = (const float*)d_in[2];
    const float* W2 = (const float*)d_in[3];
    const float* b2 = (const float*)d_in[4];
    const float* W3 = (const float*)d_in[5];
    const float* b3 = (const float*)d_in[6];

    const int n = in_sizes[0] / 8;       // 1,048,576 rows
    const int threads = n / R;           // rows per thread = R
    dim3 block(256), grid(threads / 256);

    sinkhorn_fused<<<grid, block, 0, stream>>>(margins, W1, b1, W2, b2, W3, b3,
                                               (float*)d_out, n);
}

// Round 2
// 132.387 us; speedup vs baseline: 1.2705x; 1.2705x over previous
//
#include <hip/hip_runtime.h>
#include <math.h>

// SinkhornM round 2 (fixed epilogue):
//  - LDS-staged weights, ds_read_b128 broadcast in the MLP.
//  - W3 transposed to (9,16) for float4 reads.
//  - Sinkhorn in u/v scaling-vector form (exact same math, fewer ops).
//  - R=2 rows/thread, wave-interleaved.

#define EPS_F 1e-12f
#define QLOW  0.02f
#define QSPAN 0.96f

constexpr int R = 2;

__device__ __forceinline__ float frcp(float x) { return __builtin_amdgcn_rcpf(x); }
__device__ __forceinline__ float fsig(float x) { return frcp(1.0f + __expf(-x)); }

__global__ __launch_bounds__(256) void sinkhorn_fused(
    const float* __restrict__ margins,
    const float* __restrict__ W1, const float* __restrict__ b1,
    const float* __restrict__ W2, const float* __restrict__ b2,
    const float* __restrict__ W3, const float* __restrict__ b3,
    float* __restrict__ out, int n)
{
    __shared__ __align__(16) float sW1[256];   // (8,32) row-major
    __shared__ __align__(16) float sW2[512];   // (32,16) row-major
    __shared__ __align__(16) float sW3T[144];  // (9,16): sW3T[j*16+k] = W3[k*9+j]
    __shared__ __align__(16) float sB1[32];
    __shared__ __align__(16) float sB2[16];
    __shared__ __align__(16) float sB3[12];

    {
        const int t = threadIdx.x;
        sW1[t] = W1[t];
        sW2[t] = W2[t];
        sW2[t + 256] = W2[t + 256];
        if (t < 144) { const int k = t / 9, j = t - 9 * k; sW3T[j * 16 + k] = W3[t]; }
        if (t < 32) sB1[t] = b1[t];
        if (t < 16) sB2[t] = b2[t];
        if (t < 9)  sB3[t] = b3[t];
    }
    __syncthreads();

    const float4* __restrict__ sW1v  = (const float4*)sW1;
    const float4* __restrict__ sW2v  = (const float4*)sW2;
    const float4* __restrict__ sW3Tv = (const float4*)sW3T;

    const int tid  = blockIdx.x * blockDim.x + threadIdx.x;
    const int lane = tid & 63;
    const int base = (tid >> 6) * (64 * R) + lane;  // rows base, base+64

    const float4* __restrict__ m4 = (const float4*)margins;

    float m[R][8];
#pragma unroll
    for (int r = 0; r < R; ++r) {
        const int row = base + 64 * r;
        const float4 a0 = m4[row * 2 + 0];
        const float4 a1 = m4[row * 2 + 1];
        m[r][0] = a0.x; m[r][1] = a0.y; m[r][2] = a0.z; m[r][3] = a0.w;
        m[r][4] = a1.x; m[r][5] = a1.y; m[r][6] = a1.z; m[r][7] = a1.w;
    }

    float h1[R][32];
#pragma unroll
    for (int j = 0; j < 32; ++j) {
        const float bb = sB1[j];
#pragma unroll
        for (int r = 0; r < R; ++r) h1[r][j] = bb;
    }
#pragma unroll
    for (int k = 0; k < 8; ++k) {
#pragma unroll
        for (int j4 = 0; j4 < 8; ++j4) {
            const float4 w = sW1v[k * 8 + j4];
#pragma unroll
            for (int r = 0; r < R; ++r) {
                h1[r][j4*4+0] = fmaf(m[r][k], w.x, h1[r][j4*4+0]);
                h1[r][j4*4+1] = fmaf(m[r][k], w.y, h1[r][j4*4+1]);
                h1[r][j4*4+2] = fmaf(m[r][k], w.z, h1[r][j4*4+2]);
                h1[r][j4*4+3] = fmaf(m[r][k], w.w, h1[r][j4*4+3]);
            }
        }
    }
#pragma unroll
    for (int j = 0; j < 32; ++j)
#pragma unroll
        for (int r = 0; r < R; ++r) h1[r][j] = fmaxf(h1[r][j], 0.0f);

    float h2[R][16];
#pragma unroll
    for (int j = 0; j < 16; ++j) {
        const float bb = sB2[j];
#pragma unroll
        for (int r = 0; r < R; ++r) h2[r][j] = bb;
    }
#pragma unroll
    for (int k = 0; k < 32; ++k) {
#pragma unroll
        for (int j4 = 0; j4 < 4; ++j4) {
            const float4 w = sW2v[k * 4 + j4];
#pragma unroll
            for (int r = 0; r < R; ++r) {
                h2[r][j4*4+0] = fmaf(h1[r][k], w.x, h2[r][j4*4+0]);
                h2[r][j4*4+1] = fmaf(h1[r][k], w.y, h2[r][j4*4+1]);
                h2[r][j4*4+2] = fmaf(h1[r][k], w.z, h2[r][j4*4+2]);
                h2[r][j4*4+3] = fmaf(h1[r][k], w.w, h2[r][j4*4+3]);
            }
        }
    }
#pragma unroll
    for (int j = 0; j < 16; ++j)
#pragma unroll
        for (int r = 0; r < R; ++r) h2[r][j] = fmaxf(h2[r][j], 0.0f);

    float p[R][9];
#pragma unroll
    for (int j = 0; j < 9; ++j) {
#pragma unroll
        for (int r = 0; r < R; ++r) p[r][j] = sB3[j];
#pragma unroll
        for (int k4 = 0; k4 < 4; ++k4) {
            const float4 w = sW3Tv[j * 4 + k4];
#pragma unroll
            for (int r = 0; r < R; ++r) {
                p[r][j] = fmaf(h2[r][k4*4+0], w.x, p[r][j]);
                p[r][j] = fmaf(h2[r][k4*4+1], w.y, p[r][j]);
                p[r][j] = fmaf(h2[r][k4*4+2], w.z, p[r][j]);
                p[r][j] = fmaf(h2[r][k4*4+3], w.w, p[r][j]);
            }
        }
    }

    float4* __restrict__ o4 = (float4*)out;
    float* __restrict__ oV = out + (size_t)n * 16;

#pragma unroll
    for (int r = 0; r < R; ++r) {
        const int row = base + 64 * r;

        const float e0 = __expf(p[r][0]);
        const float e1 = __expf(p[r][1]);
        const float e2 = __expf(p[r][2]);
        const float e3 = __expf(p[r][3]);
        const float col0 = sqrtf(e0 * e1);
        const float col1 = sqrtf(e2 * e3);
        const float rw0  = sqrtf(e0 * e2);
        const float rw1  = sqrtf(e1 * e3);
        const float corn = sqrtf(rw0 * rw1);

        const float a00 = e0,  a01 = e1,  a02 = col0;
        const float a10 = e2,  a11 = e3,  a12 = col1;
        const float a20 = rw0, a21 = rw1, a22 = corn;

        const float s4 = QLOW + QSPAN * fsig(p[r][4]);
        const float s5 = QLOW + QSPAN * fsig(p[r][5]);
        const float s6 = QLOW + QSPAN * fsig(p[r][6]);
        const float s7 = QLOW + QSPAN * fsig(p[r][7]);

        const float M0 = m[r][0], M1 = m[r][1], M2 = m[r][2];
        const float F0 = m[r][3], F1 = m[r][4], F2 = m[r][5];

        const float rm0 = M0 * s4, rm1 = M1 * s5, rm2 = M2;
        const float cm0 = F0 * s6, cm1 = F1 * s7, cm2 = F2;
        const float um0 = M0 * (1.0f - s4);
        const float um1 = M1 * (1.0f - s5);
        const float uf0 = F0 * (1.0f - s6);
        const float uf1 = F1 * (1.0f - s7);

        float u0 = 1.0f, u1 = 1.0f, u2 = 1.0f;
        float v0 = 1.0f, v1 = 1.0f, v2 = 1.0f;
#pragma unroll
        for (int it = 0; it < 10; ++it) {
            float t0 = fmaf(a02, v2, fmaf(a01, v1, a00 * v0));
            float t1 = fmaf(a12, v2, fmaf(a11, v1, a10 * v0));
            float t2 = fmaf(a22, v2, fmaf(a21, v1, a20 * v0));
            u0 = u0 * rm0 * frcp(fmaf(u0, t0, EPS_F));
            u1 = u1 * rm1 * frcp(fmaf(u1, t1, EPS_F));
            u2 = u2 * rm2 * frcp(fmaf(u2, t2, EPS_F));
            float s0 = fmaf(a20, u2, fmaf(a10, u1, a00 * u0));
            float s1 = fmaf(a21, u2, fmaf(a11, u1, a01 * u0));
            float s2 = fmaf(a22, u2, fmaf(a12, u1, a02 * u0));
            v0 = v0 * cm0 * frcp(fmaf(v0, s0, EPS_F));
            v1 = v1 * cm1 * frcp(fmaf(v1, s1, EPS_F));
            v2 = v2 * cm2 * frcp(fmaf(v2, s2, EPS_F));
        }

        const float A0f = u0 * a00 * v0, A1f = u0 * a01 * v1, A2f = u0 * a02 * v2;
        const float A3f = u1 * a10 * v0, A4f = u1 * a11 * v1, A5f = u1 * a12 * v2;
        const float A6f = u2 * a20 * v0, A7f = u2 * a21 * v1, A8f = u2 * a22 * v2;

        o4[row * 4 + 0] = make_float4(A0f, A1f, A2f, um0);
        o4[row * 4 + 1] = make_float4(A3f, A4f, A5f, um1);
        o4[row * 4 + 2] = make_float4(A6f, A7f, A8f, 0.0f);
        o4[row * 4 + 3] = make_float4(uf0, uf1, 0.0f, 0.0f);
        oV[row] = __expf(p[r][8]);
    }
}

extern "C" void kernel_launch(void* const* d_in, const int* in_sizes, int n_in,
                              void* d_out, int out_size, void* d_ws, size_t ws_size,
                              hipStream_t stream) {
    const float* margins = (const float*)d_in[0];
    const float* W1 = (const float*)d_in[1];
    const float* b1 = (const float*)d_in[2];
    const float* W2 = (const float*)d_in[3];
    const float* b2 = (const float*)d_in[4];
    const float* W3 = (const float*)d_in[5];
    const float* b3 = (const float*)d_in[6];

    const int n = in_sizes[0] / 8;       // 1,048,576 rows
    const int threads = n / R;
    dim3 block(256), grid(threads / 256);

    sinkhorn_fused<<<grid, block, 0, stream>>>(margins, W1, b1, W2, b2, W3, b3,
                                               (float*)d_out, n);
}